// Round 1
// baseline (436.301 us; speedup 1.0000x reference)
//
#include <hip/hip_runtime.h>

// Problem constants (C,H,W,hi,wi) = (32,32,32,32,32)
constexpr int NPIX  = 32 * 32 * 32;   // C*H*W = 32768 pixels
constexpr int TILE  = 32 * 32;        // hi*wi = 1024 elements per pixel
constexpr int NBIG  = NPIX * TILE;    // elements of lx_in / ux_in
constexpr int THREADS = 256;          // 4 elements per thread (float4)

__global__ __launch_bounds__(THREADS)
void relu_conv_kernel(const float* __restrict__ lx_in,
                      const float* __restrict__ ux_in,
                      const float* __restrict__ lc_in,
                      const float* __restrict__ uc_in,
                      const float* __restrict__ x_min,
                      const float* __restrict__ x_max,
                      float* __restrict__ lx_out,
                      float* __restrict__ ux_out,
                      float* __restrict__ lc_out,
                      float* __restrict__ uc_out)
{
    const int p = blockIdx.x;          // pixel index in [0, NPIX)
    const int t = threadIdx.x;
    const long base = (long)p * TILE + t * 4;

    // One float4 of lx/ux per thread -> tile read exactly once from HBM.
    const float4 lx = *(const float4*)(lx_in + base);
    const float4 ux = *(const float4*)(ux_in + base);
    const float4 mn = *(const float4*)(x_min + t * 4);
    const float4 mx = *(const float4*)(x_max + t * 4);

    // Masked partial sums: lower uses min when lx>0, max when lx<0, 0 at 0;
    // upper uses max when ux>0, min when ux<0, 0 at 0.
    float sl = 0.f, su = 0.f;
    {
        const float a[4]  = {lx.x, lx.y, lx.z, lx.w};
        const float b[4]  = {ux.x, ux.y, ux.z, ux.w};
        const float lo[4] = {mn.x, mn.y, mn.z, mn.w};
        const float hi[4] = {mx.x, mx.y, mx.z, mx.w};
        #pragma unroll
        for (int i = 0; i < 4; ++i) {
            const float ml = a[i] > 0.f ? lo[i] : (a[i] < 0.f ? hi[i] : 0.f);
            const float mu = b[i] > 0.f ? hi[i] : (b[i] < 0.f ? lo[i] : 0.f);
            sl += ml * a[i];
            su += mu * b[i];
        }
    }

    // Wave (64-lane) butterfly-equivalent tree reduction.
    #pragma unroll
    for (int off = 32; off > 0; off >>= 1) {
        sl += __shfl_down(sl, off, 64);
        su += __shfl_down(su, off, 64);
    }

    __shared__ float rl[4], ru[4];
    const int wave = t >> 6;
    if ((t & 63) == 0) { rl[wave] = sl; ru[wave] = su; }
    __syncthreads();

    const float lc = lc_in[p];
    const float uc = uc_in[p];
    const float l = (rl[0] + rl[1]) + (rl[2] + rl[3]) + lc;
    const float u = (ru[0] + ru[1]) + (ru[2] + ru[3]) + uc;

    const bool alive = (l >= 0.f);
    const bool cross = (l < 0.f) && (u > 0.f);
    float slope = cross ? (u / (u - l)) : 1.f;
    slope = fminf(fmaxf(slope, 0.f), 1.f);

    // lx_out = alive ? lx : 0
    // ux_out = alive ? ux : (cross ? slope*ux : 0)
    const float fl = alive ? 1.f : 0.f;
    const float fu = alive ? 1.f : (cross ? slope : 0.f);

    float4 lo4, uo4;
    lo4.x = fl * lx.x; lo4.y = fl * lx.y; lo4.z = fl * lx.z; lo4.w = fl * lx.w;
    uo4.x = fu * ux.x; uo4.y = fu * ux.y; uo4.z = fu * ux.z; uo4.w = fu * ux.w;

    *(float4*)(lx_out + base) = lo4;
    *(float4*)(ux_out + base) = uo4;

    if (t == 0) {
        lc_out[p] = alive ? lc : 0.f;
        uc_out[p] = alive ? uc : (cross ? (slope * uc - slope * l) : 0.f);
    }
}

extern "C" void kernel_launch(void* const* d_in, const int* in_sizes, int n_in,
                              void* d_out, int out_size, void* d_ws, size_t ws_size,
                              hipStream_t stream) {
    const float* lx_in = (const float*)d_in[0];
    const float* ux_in = (const float*)d_in[1];
    const float* lc_in = (const float*)d_in[2];
    const float* uc_in = (const float*)d_in[3];
    const float* x_min = (const float*)d_in[4];
    const float* x_max = (const float*)d_in[5];

    float* out = (float*)d_out;
    float* lx_out = out;                       // NBIG
    float* ux_out = out + (size_t)NBIG;        // NBIG
    float* lc_out = out + (size_t)2 * NBIG;    // NPIX
    float* uc_out = lc_out + NPIX;             // NPIX

    relu_conv_kernel<<<dim3(NPIX), dim3(THREADS), 0, stream>>>(
        lx_in, ux_in, lc_in, uc_in, x_min, x_max,
        lx_out, ux_out, lc_out, uc_out);
}

// Round 3
// 424.039 us; speedup vs baseline: 1.0289x; 1.0289x over previous
//
#include <hip/hip_runtime.h>

// Problem constants (C,H,W,hi,wi) = (32,32,32,32,32)
constexpr int NPIX  = 32 * 32 * 32;     // C*H*W pixels
constexpr int TILE  = 32 * 32;          // hi*wi elements per pixel
constexpr long NBIG = (long)NPIX * TILE;
constexpr int THREADS = 256;            // 4 waves -> 4 independent pixels/block
constexpr int PIX_PER_BLOCK = THREADS / 64;

// Native Clang vector type: accepted by __builtin_nontemporal_* (HIP's
// float4 struct is not).
typedef float v4f __attribute__((ext_vector_type(4)));

__global__ __launch_bounds__(THREADS)
void relu_conv_kernel(const float* __restrict__ lx_in,
                      const float* __restrict__ ux_in,
                      const float* __restrict__ lc_in,
                      const float* __restrict__ uc_in,
                      const float* __restrict__ x_min,
                      const float* __restrict__ x_max,
                      float* __restrict__ lx_out,
                      float* __restrict__ ux_out,
                      float* __restrict__ lc_out,
                      float* __restrict__ uc_out)
{
    const int lane = threadIdx.x & 63;
    const int wave = threadIdx.x >> 6;
    const int p = blockIdx.x * PIX_PER_BLOCK + wave;   // pixel index

    const long base = (long)p * TILE;

    // Lane i covers tile offsets {lane*4 + j*256 : j=0..3}; each wave load is
    // 64 lanes x 16 B = 1 KiB contiguous. 8 streaming loads in flight/lane.
    v4f lx[4], ux[4];
    float sl = 0.f, su = 0.f;
    #pragma unroll
    for (int j = 0; j < 4; ++j) {
        const int off = lane * 4 + j * 256;
        lx[j] = __builtin_nontemporal_load(
                    reinterpret_cast<const v4f*>(lx_in + base + off));
        ux[j] = __builtin_nontemporal_load(
                    reinterpret_cast<const v4f*>(ux_in + base + off));
        const v4f mn = *reinterpret_cast<const v4f*>(x_min + off);
        const v4f mx = *reinterpret_cast<const v4f*>(x_max + off);

        #pragma unroll
        for (int k = 0; k < 4; ++k) {
            const float a = lx[j][k];
            const float b = ux[j][k];
            const float ml = a > 0.f ? mn[k] : (a < 0.f ? mx[k] : 0.f);
            const float mu = b > 0.f ? mx[k] : (b < 0.f ? mn[k] : 0.f);
            sl += ml * a;
            su += mu * b;
        }
    }

    // Wave-wide butterfly reduction: all 64 lanes end with the full sums.
    #pragma unroll
    for (int m = 32; m > 0; m >>= 1) {
        sl += __shfl_xor(sl, m, 64);
        su += __shfl_xor(su, m, 64);
    }

    const float lc = lc_in[p];
    const float uc = uc_in[p];
    const float l = sl + lc;
    const float u = su + uc;

    const bool alive = (l >= 0.f);
    const bool cross = (l < 0.f) && (u > 0.f);
    float slope = cross ? (u / (u - l)) : 1.f;
    slope = fminf(fmaxf(slope, 0.f), 1.f);

    const float fl = alive ? 1.f : 0.f;
    const float fu = alive ? 1.f : (cross ? slope : 0.f);

    #pragma unroll
    for (int j = 0; j < 4; ++j) {
        const int off = lane * 4 + j * 256;
        v4f lo4 = lx[j] * fl;
        v4f uo4 = ux[j] * fu;
        __builtin_nontemporal_store(lo4,
            reinterpret_cast<v4f*>(lx_out + base + off));
        __builtin_nontemporal_store(uo4,
            reinterpret_cast<v4f*>(ux_out + base + off));
    }

    if (lane == 0) {
        lc_out[p] = alive ? lc : 0.f;
        uc_out[p] = alive ? uc : (cross ? (slope * uc - slope * l) : 0.f);
    }
}

extern "C" void kernel_launch(void* const* d_in, const int* in_sizes, int n_in,
                              void* d_out, int out_size, void* d_ws, size_t ws_size,
                              hipStream_t stream) {
    const float* lx_in = (const float*)d_in[0];
    const float* ux_in = (const float*)d_in[1];
    const float* lc_in = (const float*)d_in[2];
    const float* uc_in = (const float*)d_in[3];
    const float* x_min = (const float*)d_in[4];
    const float* x_max = (const float*)d_in[5];

    float* out = (float*)d_out;
    float* lx_out = out;                         // NBIG
    float* ux_out = out + NBIG;                  // NBIG
    float* lc_out = out + 2 * NBIG;              // NPIX
    float* uc_out = lc_out + NPIX;               // NPIX

    relu_conv_kernel<<<dim3(NPIX / PIX_PER_BLOCK), dim3(THREADS), 0, stream>>>(
        lx_in, ux_in, lc_in, uc_in, x_min, x_max,
        lx_out, ux_out, lc_out, uc_out);
}